// Round 3
// baseline (170.036 us; speedup 1.0000x reference)
//
#include <hip/hip_runtime.h>
#include <hip/hip_bf16.h>
#include <math.h>

// Problem constants (from reference)
#define INPUT_DIM 30000
#define UNITS     2048
#define NNZ       500000
#define BATCH     32

// ---------------------------------------------------------------------------
// Kernel 1: transpose x [32][30000] -> xt [30000][32]
// ---------------------------------------------------------------------------
__global__ __launch_bounds__(256) void transpose_k(const float* __restrict__ x,
                                                   float* __restrict__ xt) {
    int tid = blockIdx.x * 256 + threadIdx.x;     // 0 .. 960000-1
    int i = tid >> 5;                             // input-dim index
    int b = tid & 31;                             // batch index
    xt[tid] = x[b * INPUT_DIM + i];
}

// ---------------------------------------------------------------------------
// Kernel 2: scatter-accumulate. ONE THREAD PER ENTRY x 8 batch rows.
// grid = (nchunk, 4). Each thread: coalesced idx (16B) + kv (4B) loads,
// 32B contiguous xt row-slice gather (2x float4), 8 LDS atomicAdds.
// Per-thread trip count ~3.8 (nchunk=128) -> few serialized latency trips.
// LDS slot swizzle (j+c)&7 spreads the 8 sequential ds_adds over all 32
// banks (unswizzled: 16-way conflict). acc[c*8 + s] holds batch (s-c)&7.
// ---------------------------------------------------------------------------
__global__ __launch_bounds__(1024) void scatter_k(const int* __restrict__ idx,
                                                  const float* __restrict__ kv,
                                                  const float* __restrict__ xt,
                                                  float* __restrict__ part,
                                                  int nchunk) {
    __shared__ float acc[UNITS * 8];              // 64 KB

    const int chunk = blockIdx.x;
    const int bg    = blockIdx.y;                 // batch group 0..3

    {
        float4* a4 = (float4*)acc;
        #pragma unroll
        for (int t = threadIdx.x; t < UNITS * 2; t += 1024)
            a4[t] = make_float4(0.f, 0.f, 0.f, 0.f);
    }
    __syncthreads();

    // int64 vs int32 index detection (uniform): int64 LE -> high words zero.
    const bool is64 = ((idx[3] | idx[5] | idx[7]) == 0);

    const int e0 = (int)((long long)NNZ * chunk / nchunk);
    const int e1 = (int)((long long)NNZ * (chunk + 1) / nchunk);
    const int boff = bg * 8;

    if (is64) {
        const int4* __restrict__ p = (const int4*)idx;   // {row_lo,row_hi,col_lo,col_hi}
        #pragma unroll 2
        for (int e = e0 + threadIdx.x; e < e1; e += 1024) {
            int4  q = p[e];
            float v = kv[e];
            const float4* __restrict__ xr = (const float4*)(xt + q.x * 32 + boff);
            float4 x0 = xr[0];
            float4 x1 = xr[1];
            float* __restrict__ base = acc + q.z * 8;
            const int sw = q.z & 7;
            atomicAdd(base + ((sw + 0) & 7), v * x0.x);
            atomicAdd(base + ((sw + 1) & 7), v * x0.y);
            atomicAdd(base + ((sw + 2) & 7), v * x0.z);
            atomicAdd(base + ((sw + 3) & 7), v * x0.w);
            atomicAdd(base + ((sw + 4) & 7), v * x1.x);
            atomicAdd(base + ((sw + 5) & 7), v * x1.y);
            atomicAdd(base + ((sw + 6) & 7), v * x1.z);
            atomicAdd(base + ((sw + 7) & 7), v * x1.w);
        }
    } else {
        const int2* __restrict__ p = (const int2*)idx;   // {row, col}
        #pragma unroll 2
        for (int e = e0 + threadIdx.x; e < e1; e += 1024) {
            int2  q = p[e];
            float v = kv[e];
            const float4* __restrict__ xr = (const float4*)(xt + q.x * 32 + boff);
            float4 x0 = xr[0];
            float4 x1 = xr[1];
            float* __restrict__ base = acc + q.y * 8;
            const int sw = q.y & 7;
            atomicAdd(base + ((sw + 0) & 7), v * x0.x);
            atomicAdd(base + ((sw + 1) & 7), v * x0.y);
            atomicAdd(base + ((sw + 2) & 7), v * x0.z);
            atomicAdd(base + ((sw + 3) & 7), v * x0.w);
            atomicAdd(base + ((sw + 4) & 7), v * x1.x);
            atomicAdd(base + ((sw + 5) & 7), v * x1.y);
            atomicAdd(base + ((sw + 6) & 7), v * x1.z);
            atomicAdd(base + ((sw + 7) & 7), v * x1.w);
        }
    }
    __syncthreads();

    float4* __restrict__ dst = (float4*)(part + (size_t)(bg * nchunk + chunk) * (UNITS * 8));
    const float4* __restrict__ src = (const float4*)acc;
    #pragma unroll
    for (int t = threadIdx.x; t < UNITS * 2; t += 1024) dst[t] = src[t];
}

// ---------------------------------------------------------------------------
// Kernel 3: reduce partials over chunks (coalesced float4), un-swizzle,
// add bias, tanh, write out [32][2048]. grid = (16, 4) x 256 threads.
// Slab element f = c*8 + s holds batch (s - c) & 7 of the group.
// ---------------------------------------------------------------------------
__global__ __launch_bounds__(256) void reduce_k(const float* __restrict__ part,
                                                const float* __restrict__ bias,
                                                float* __restrict__ out,
                                                int nchunk) {
    const int bg = blockIdx.y;
    const int v  = blockIdx.x * 256 + threadIdx.x;   // float4 slot 0..4095
    const int f  = v * 4;                            // slab element index
    const int s0 = f & 7;                            // 0 or 4
    const int c  = f >> 3;

    const float4* __restrict__ p =
        (const float4*)(part + (size_t)bg * nchunk * (UNITS * 8)) + v;
    float4 s = make_float4(0.f, 0.f, 0.f, 0.f);
    #pragma unroll 4
    for (int k = 0; k < nchunk; ++k) {
        float4 q = p[(size_t)k * (UNITS * 2)];
        s.x += q.x; s.y += q.y; s.z += q.z; s.w += q.w;
    }
    const float bs = bias[c];
    const int   sw = c & 7;
    const int   b0 = bg * 8;
    out[(b0 + ((s0 + 0 - sw) & 7)) * UNITS + c] = tanhf(s.x + bs);
    out[(b0 + ((s0 + 1 - sw) & 7)) * UNITS + c] = tanhf(s.y + bs);
    out[(b0 + ((s0 + 2 - sw) & 7)) * UNITS + c] = tanhf(s.z + bs);
    out[(b0 + ((s0 + 3 - sw) & 7)) * UNITS + c] = tanhf(s.w + bs);
}

// ---------------------------------------------------------------------------
extern "C" void kernel_launch(void* const* d_in, const int* in_sizes, int n_in,
                              void* d_out, int out_size, void* d_ws, size_t ws_size,
                              hipStream_t stream) {
    const float* x    = (const float*)d_in[0];
    const float* kv   = (const float*)d_in[1];
    const float* bias = (const float*)d_in[2];
    const int*   idx  = (const int*)d_in[3];
    float*       out  = (float*)d_out;

    const size_t xt_bytes = (size_t)INPUT_DIM * BATCH * sizeof(float); // 3.84 MB
    float* xt = (float*)d_ws;

    // largest chunk count whose partial buffer fits the workspace
    int nchunk = 1;
    const int cand[] = {128, 112, 96, 80, 64, 48, 32, 16, 8, 4, 2, 1};
    for (int i = 0; i < 12; ++i) {
        size_t need = xt_bytes + (size_t)cand[i] * 4 * (UNITS * 8) * sizeof(float);
        if (need <= ws_size) { nchunk = cand[i]; break; }
    }
    float* part = (float*)((char*)d_ws + xt_bytes);

    transpose_k<<<(INPUT_DIM * BATCH) / 256, 256, 0, stream>>>(x, xt);
    scatter_k<<<dim3(nchunk, 4), 1024, 0, stream>>>(idx, kv, xt, part, nchunk);
    reduce_k<<<dim3(16, 4), 256, 0, stream>>>(part, bias, out, nchunk);
}